// Round 11
// baseline (140.034 us; speedup 1.0000x reference)
//
#include <hip/hip_runtime.h>
#include <type_traits>

typedef __attribute__((ext_vector_type(8))) short short8;
typedef __attribute__((ext_vector_type(4))) short short4v;
typedef __attribute__((ext_vector_type(2))) short short2v;
typedef __attribute__((ext_vector_type(4))) float f32x4;
typedef unsigned short u16;
typedef unsigned int u32;

#define N_EDGES 448

// ws layout (u16 units); all-bf16 packs
#define WS_ADJA 0                    // 4096: A_norm, MFMA A-operand pack
#define WS_ADJB 4096                 // 4096: A_norm^T, MFMA B-operand pack
#define WS_W1   8192                 // 256x512, wave-grouped [w][kk][s4]
#define WS_W2   139264               // 512x512, wave-grouped [w][kk][s4]
#define WS_W3   401408               // 512x256, wave-grouped [w][kk][s2]
#define WS_DUM  532480               // dummy 256 (KEYED) | b1 512 | b2 512 | b3 256
#define WS_B1   (WS_DUM + 256)
#define WS_B2   (WS_DUM + 768)
#define WS_B3   (WS_DUM + 1280)
#define WS_QE   534528               // 1024x256 qembs as KEYED bf16, row-major
#define WS_FLAG 796672               // u32: 1 = f32 inputs, 0 = bf16

__device__ __forceinline__ float bf2f(u16 v) {
    u32 u = ((u32)v) << 16;
    return __builtin_bit_cast(float, u);
}
__device__ __forceinline__ u16 f2bf(float f) {          // RNE (prep)
    u32 u = __builtin_bit_cast(u32, f);
    u32 r = u + 0x7FFFu + ((u >> 16) & 1u);
    return (u16)(r >> 16);
}
__device__ __forceinline__ u16 f2bf_fast(float f) {     // round-half-up (hot)
    u32 u = __builtin_bit_cast(u32, f);
    return (u16)((u + 0x8000u) >> 16);
}
__device__ __forceinline__ float ldf(const void* p, int idx, u32 isf32) {
    return isf32 ? ((const float*)p)[idx] : bf2f(((const u16*)p)[idx]);
}
// monotone bf16 <-> i16 key (involution): negatives get magnitude bits flipped,
// so signed-i16 compare == float compare. pk_max(i16) then equals fmax exactly.
__device__ __forceinline__ u16 keyb(u16 b) {
    return (u16)(b ^ ((u16)(((u16)((short)b >> 15)) >> 1)));
}
__device__ __forceinline__ u32 pkmax(u32 a, u32 b) {    // 2-lane packed i16 max
    short2v x = __builtin_bit_cast(short2v, a);
    short2v y = __builtin_bit_cast(short2v, b);
    short2v r = __builtin_elementwise_max(x, y);
    return __builtin_bit_cast(u32, r);
}

// ---------------------------------------------------------------------------
// prep: 512 blocks x 512 threads (proven, unchanged from R6).
//   all blocks: 2 weight chunks (t<128) + qembs->KEYED bf16 copy (t>=256)
//   block 0: adjacency + flag;  block 1: biases (plain) / dummy (KEYED)
// W packs wave-grouped: chunk = ((nt>>l2)*K32 + kk)<<l2 | (nt&(nsw-1)) so the
// fused K-loop uses ONE address stream + imm offsets (R6 spill fix, proven).
// ---------------------------------------------------------------------------
__global__ __launch_bounds__(512) void prep(
    const int* __restrict__ eidx, const void* __restrict__ ew,
    const void* __restrict__ qembs, const void* __restrict__ dummy,
    const void* __restrict__ W1, const void* __restrict__ b1,
    const void* __restrict__ W2, const void* __restrict__ b2,
    const void* __restrict__ W3, const void* __restrict__ b3,
    u16* __restrict__ ws) {
    const int t = threadIdx.x, bb = blockIdx.x;
    __shared__ u32 s_isf;
    if (t < 64) {
        const u16* qs = (const u16*)qembs;
        int c = 0;
#pragma unroll
        for (int j = 0; j < 4; j++) {
            u16 v = qs[(t * 4 + j) * 2];
            u32 e = (v >> 7) & 0xFF;
            c += (e >= 100 && e <= 134) ? 1 : 0;
        }
#pragma unroll
        for (int off = 32; off > 0; off >>= 1) c += __shfl_down(c, off, 64);
        if (t == 0) s_isf = (c < 128) ? 1u : 0u;
    }
    __syncthreads();
    const u32 isf32 = s_isf;

    if (t < 128) {
        const int bw = bb * 2 + (t >> 6);
        const int tl = t & 63;
        const void* src;
        int N, K32, dst, nt, kk, l2;
        if (bw < 256)      { src = W1; N = 512; K32 = 8;  dst = WS_W1; nt = bw / 8;          kk = bw % 8;         l2 = 2; }
        else if (bw < 768) { src = W2; N = 512; K32 = 16; dst = WS_W2; nt = (bw - 256) / 16; kk = (bw - 256) % 16; l2 = 2; }
        else               { src = W3; N = 256; K32 = 16; dst = WS_W3; nt = (bw - 768) / 16; kk = (bw - 768) % 16; l2 = 1; }
        const int col = nt * 16 + (tl & 15);
        const int krow = kk * 32 + (tl >> 4) * 8;
        u16 v[8];
#pragma unroll
        for (int j = 0; j < 8; j++) v[j] = f2bf(ldf(src, (krow + j) * N + col, isf32));
        const int chunk = ((((nt >> l2) * K32 + kk) << l2) | (nt & ((1 << l2) - 1)));
        u16* o = ws + dst + chunk * 512 + tl * 8;
#pragma unroll
        for (int j = 0; j < 8; j++) o[j] = v[j];
    }
    if (t >= 256) {
        const int base = bb * 512 + (t - 256) * 2;
        ws[WS_QE + base]     = keyb(f2bf(ldf(qembs, base, isf32)));
        ws[WS_QE + base + 1] = keyb(f2bf(ldf(qembs, base + 1, isf32)));
    }
    if (bb == 1) {
#pragma unroll
        for (int j = 0; j < 4; j++) {
            int i = t + j * 512;
            if (i < 1792) {
                u16 o;
                if (i < 256)       o = keyb(f2bf(ldf(dummy, i, isf32)));
                else if (i < 768)  o = f2bf(ldf(b1, i - 256, isf32));
                else if (i < 1280) o = f2bf(ldf(b2, i - 768, isf32));
                else               o = f2bf(ldf(b3, i - 1280, isf32));
                ws[WS_DUM + i] = o;
            }
        }
    }
    if (bb == 0) {
        __shared__ float A[4096];
        __shared__ float deg[64];
        __shared__ float dinv[64];
        __shared__ int er[N_EDGES];
        __shared__ int ec[N_EDGES];
        __shared__ float ewf[N_EDGES];
        if (t < N_EDGES) {
            er[t] = eidx[t];
            ec[t] = eidx[N_EDGES + t];
            ewf[t] = ldf(ew, t, isf32);
        }
        if (t < 64) deg[t] = 1.0f;
        for (int i = t; i < 4096; i += 512) A[i] = 0.f;
        __syncthreads();
        if (t < N_EDGES) atomicAdd(&deg[ec[t]], ewf[t]);
        __syncthreads();
        if (t < 64) dinv[t] = 1.0f / sqrtf(deg[t]);
        __syncthreads();
        if (t < N_EDGES) atomicAdd(&A[ec[t] * 64 + er[t]], dinv[er[t]] * ewf[t] * dinv[ec[t]]);
        __syncthreads();
        if (t < 64) A[t * 64 + t] += dinv[t] * dinv[t];
        __syncthreads();
        for (int i = t; i < 4096; i += 512) {
            int chunk = i >> 9, m = (i >> 3) & 63, j = i & 7;
            ws[WS_ADJA + i] = f2bf(A[m * 64 + chunk * 8 + j]);
        }
        for (int i = t; i < 4096; i += 512) {
            int chunk = i >> 9, l = (i >> 3) & 63, j = i & 7;
            int ntc = chunk >> 1, kk = chunk & 1;
            int k = kk * 32 + (l >> 4) * 8 + j;
            int c2 = ntc * 16 + (l & 15);
            ws[WS_ADJB + i] = f2bf(A[c2 * 64 + k]);
        }
        if (t == 0) *(u32*)(ws + WS_FLAG) = isf32;
    }
}

// ---------------------------------------------------------------------------
// fused R10 (resubmitted R11 — R10 bench was an infra failure, no data):
// R9 base (512 blocks x 512 threads, 1 element/block, 2 blocks/CU)
// + two LDS-traffic cuts (-512 KB/elem, -20%), the only lever that has paid
// (R6: -30% traffic -> -9% wall; R9 proved barrier overlap is not the bound):
//  (a) adjB h=0 fragments hoisted to 16 regs per layerT epilogue (loaded from
//      ADJB_S AFTER the mid-barrier, when K-loop regs are dead: peak ~110 of
//      128 unified — avoids R1/R4/R5 spill traps). Halves adjB LDS reads.
//  (b) final phase stores relu(accv+b3) DIRECT from registers to global
//      (4x64B/32B aligned runs per instr) — deletes the 256 KB f32 staging
//      round-trip and the last 2 barriers.
// Spill gate: FETCH > 15 MB => revert.
// ---------------------------------------------------------------------------
__global__ __launch_bounds__(512, 4) void fused(
    const int* __restrict__ allocs, const u16* __restrict__ ws,
    void* __restrict__ out) {

    __shared__ __align__(16) u16 BUF[64 * 512];      // 64 KB
    __shared__ __align__(16) u16 ADJB_S[4096];       // 8 KB: A_norm^T B-pack

    const int t = threadIdx.x, bb = blockIdx.x;
    const int wave = t >> 6, lane = t & 63, quad = lane >> 4, nl = lane & 15;
    const u32 isf32 = *(const u32*)(ws + WS_FLAG);

    *(uint4*)(ADJB_S + t * 8) = *(const uint4*)(ws + WS_ADJB + t * 8);

    // ---- pooling: counting sort (2 qubits/thread), then each wave gathers
    // 8 cores -> X A-pack in BUF chunks 0..31. Aux in chunks 32+ (dead). ----
    {
        int* LIST = (int*)(BUF + 16384);
        int* CNT  = LIST + 1024;
        int* SST  = CNT + 64;
        int* WOF  = SST + 64;
        if (t < 64) CNT[t] = 0;
        __syncthreads();
        const int c0 = allocs[bb * 1024 + t];
        const int c1 = allocs[bb * 1024 + 512 + t];
        atomicAdd(&CNT[c0], 1);
        atomicAdd(&CNT[c1], 1);
        __syncthreads();
        if (t < 64) {
            int v = CNT[t], s = v;
#pragma unroll
            for (int off = 1; off < 64; off <<= 1) {
                int u = __shfl_up(s, off, 64);
                if (t >= off) s += u;
            }
            SST[t] = s - v;
            WOF[t] = s - v;
        }
        __syncthreads();
        {
            int p0 = atomicAdd(&WOF[c0], 1); LIST[p0] = t;
            int p1 = atomicAdd(&WOF[c1], 1); LIST[p1] = 512 + t;
        }
        __syncthreads();
        // wave owns cores wave*8..+7; lane owns dims lane*4..+3
        const u16* wsq = ws + WS_QE;
        const uint2 dk = *(const uint2*)(ws + WS_DUM + lane * 4);  // keyed dummy
        for (int i = 0; i < 8; i++) {
            const int c = wave * 8 + i;
            const int L = CNT[c], S = SST[c];
            u32 m0 = dk.x, m1 = dk.y;
            int j = 0;
            for (; j + 4 <= L; j += 4) {
                const int q0 = LIST[S + j],     q1 = LIST[S + j + 1];
                const int q2 = LIST[S + j + 2], q3 = LIST[S + j + 3];
                uint2 ra = *(const uint2*)(wsq + q0 * 256 + lane * 4);
                uint2 rb = *(const uint2*)(wsq + q1 * 256 + lane * 4);
                uint2 rc = *(const uint2*)(wsq + q2 * 256 + lane * 4);
                uint2 rd = *(const uint2*)(wsq + q3 * 256 + lane * 4);
                m0 = pkmax(pkmax(m0, ra.x), pkmax(rb.x, rc.x));
                m1 = pkmax(pkmax(m1, ra.y), pkmax(rb.y, rc.y));
                m0 = pkmax(m0, rd.x);
                m1 = pkmax(m1, rd.y);
            }
            for (; j < L; j++) {
                const int q = LIST[S + j];
                uint2 r = *(const uint2*)(wsq + q * 256 + lane * 4);
                m0 = pkmax(m0, r.x);
                m1 = pkmax(m1, r.y);
            }
            short4v p;                     // un-key -> exact bf16 max
            p[0] = (short)keyb((u16)(m0 & 0xffffu));
            p[1] = (short)keyb((u16)(m0 >> 16));
            p[2] = (short)keyb((u16)(m1 & 0xffffu));
            p[3] = (short)keyb((u16)(m1 >> 16));
            *(short4v*)(BUF + (lane >> 1) * 512 + c * 8 + (lane & 1) * 4) = p;
        }
    }
    __syncthreads();

    // layerT (in-place over BUF): mm1 (4 stripes/wave, s-paired bch from the
    // wave-grouped pack, ONE addr stream) -> mid barrier -> adjB h=0 frags to
    // 16 regs -> per s: transpose + agg (h0 from regs, h1 from LDS) +
    // relu/bias -> wave-owned chunks 8w..8w+7.
    auto layerT = [&](auto K32c, const u16* __restrict__ W, const u16* __restrict__ bias) {
        constexpr int K32 = decltype(K32c)::value;
        const int s0 = wave * 4;
        u16* scr = BUF + (wave * 8 + 6) * 512;
        const u16* wp = W + (wave * K32 * 4) * 512 + lane * 8;   // one addr stream
        f32x4 acc[4][4];
#pragma unroll
        for (int s = 0; s < 4; s++)
#pragma unroll
            for (int rt = 0; rt < 4; rt++) acc[s][rt] = f32x4{0.f, 0.f, 0.f, 0.f};
#pragma unroll 2
        for (int kk = 0; kk < K32; kk++) {
            short8 a[4];
#pragma unroll
            for (int rt = 0; rt < 4; rt++)
                a[rt] = *(const short8*)(BUF + (kk * 4 + quad) * 512 + (rt * 16 + nl) * 8);
            const u16* wk = wp + kk * 4 * 512;
            {
                short8 b0 = *(const short8*)(wk);
                short8 b1 = *(const short8*)(wk + 512);
#pragma unroll
                for (int rt = 0; rt < 4; rt++)
                    acc[0][rt] = __builtin_amdgcn_mfma_f32_16x16x32_bf16(a[rt], b0, acc[0][rt], 0, 0, 0);
#pragma unroll
                for (int rt = 0; rt < 4; rt++)
                    acc[1][rt] = __builtin_amdgcn_mfma_f32_16x16x32_bf16(a[rt], b1, acc[1][rt], 0, 0, 0);
            }
            {
                short8 b2 = *(const short8*)(wk + 1024);
                short8 b3 = *(const short8*)(wk + 1536);
#pragma unroll
                for (int rt = 0; rt < 4; rt++)
                    acc[2][rt] = __builtin_amdgcn_mfma_f32_16x16x32_bf16(a[rt], b2, acc[2][rt], 0, 0, 0);
#pragma unroll
                for (int rt = 0; rt < 4; rt++)
                    acc[3][rt] = __builtin_amdgcn_mfma_f32_16x16x32_bf16(a[rt], b3, acc[3][rt], 0, 0, 0);
            }
        }
        __syncthreads();   // all BUF reads complete -> in-place writes legal
        // adjB h=0 fragments in regs (K-loop operands dead; peak ~110/128)
        short8 adjB0[4];
#pragma unroll
        for (int ntc = 0; ntc < 4; ntc++)
            adjB0[ntc] = *(const short8*)(ADJB_S + (ntc * 2) * 512 + lane * 8);
#pragma unroll
        for (int s = 0; s < 4; s++) {
            const int nt = s0 + s;
            float bv[4];
#pragma unroll
            for (int rr = 0; rr < 4; rr++) bv[rr] = bf2f(bias[nt * 16 + quad * 4 + rr]);
            f32x4 agg[4];
#pragma unroll
            for (int ntc = 0; ntc < 4; ntc++) agg[ntc] = f32x4{0.f, 0.f, 0.f, 0.f};
#pragma unroll
            for (int h = 0; h < 2; h++) {
#pragma unroll
                for (int r2 = 0; r2 < 2; r2++) {
                    f32x4 v = acc[s][2 * h + r2];
                    short4v p;
#pragma unroll
                    for (int rr = 0; rr < 4; rr++) p[rr] = (short)f2bf_fast(v[rr]);
                    *(short4v*)(scr + nl * 40 + r2 * 16 + quad * 4) = p;
                }
                short8 hwf = *(const short8*)(scr + nl * 40 + quad * 8);
                if (h == 0) {
#pragma unroll
                    for (int ntc = 0; ntc < 4; ntc++)
                        agg[ntc] = __builtin_amdgcn_mfma_f32_16x16x32_bf16(hwf, adjB0[ntc], agg[ntc], 0, 0, 0);
                } else {
#pragma unroll
                    for (int ntc = 0; ntc < 4; ntc++) {
                        short8 bfrag = *(const short8*)(ADJB_S + (ntc * 2 + 1) * 512 + lane * 8);
                        agg[ntc] = __builtin_amdgcn_mfma_f32_16x16x32_bf16(hwf, bfrag, agg[ntc], 0, 0, 0);
                    }
                }
            }
#pragma unroll
            for (int ntc = 0; ntc < 4; ntc++) {
                short4v p;
#pragma unroll
                for (int rr = 0; rr < 4; rr++)
                    p[rr] = (short)f2bf_fast(fmaxf(agg[ntc][rr] + bv[rr], 0.f));
                *(short4v*)(BUF + (nt * 2 + (quad >> 1)) * 512 + (ntc * 16 + nl) * 8 + (quad & 1) * 4) = p;
            }
        }
        __syncthreads();
    };

    // layer3 (in-place): hw3 = h2 @ W3 (2 stripes/wave, paired bch) ->
    // mid barrier -> B-pack into chunks 0..31; scr in chunks 32+ (dead).
    auto layer3 = [&](const u16* __restrict__ W) {
        const u16* wp = W + (wave * 16 * 2) * 512 + lane * 8;
        f32x4 acc[2][4];
#pragma unroll
        for (int s = 0; s < 2; s++)
#pragma unroll
            for (int rt = 0; rt < 4; rt++) acc[s][rt] = f32x4{0.f, 0.f, 0.f, 0.f};
#pragma unroll 2
        for (int kk = 0; kk < 16; kk++) {
            short8 a[4];
#pragma unroll
            for (int rt = 0; rt < 4; rt++)
                a[rt] = *(const short8*)(BUF + (kk * 4 + quad) * 512 + (rt * 16 + nl) * 8);
            const u16* wk = wp + kk * 2 * 512;
            short8 b0 = *(const short8*)(wk);
            short8 b1 = *(const short8*)(wk + 512);
#pragma unroll
            for (int rt = 0; rt < 4; rt++)
                acc[0][rt] = __builtin_amdgcn_mfma_f32_16x16x32_bf16(a[rt], b0, acc[0][rt], 0, 0, 0);
#pragma unroll
            for (int rt = 0; rt < 4; rt++)
                acc[1][rt] = __builtin_amdgcn_mfma_f32_16x16x32_bf16(a[rt], b1, acc[1][rt], 0, 0, 0);
        }
        __syncthreads();   // all BUF reads complete
        u16* scr = BUF + 16384 + wave * 640;   // chunks 32+ (dead region)
#pragma unroll
        for (int s = 0; s < 2; s++) {
            const int nt = wave * 2 + s;
#pragma unroll
            for (int h = 0; h < 2; h++) {
#pragma unroll
                for (int r2 = 0; r2 < 2; r2++) {
                    f32x4 v = acc[s][2 * h + r2];
                    short4v p;
#pragma unroll
                    for (int rr = 0; rr < 4; rr++) p[rr] = (short)f2bf_fast(v[rr]);
                    *(short4v*)(scr + nl * 40 + r2 * 16 + quad * 4) = p;
                }
                short8 hwf = *(const short8*)(scr + nl * 40 + quad * 8);
                *(short8*)(BUF + (nt * 2 + h) * 512 + lane * 8) = hwf;
            }
        }
        __syncthreads();
    };

    layerT(std::integral_constant<int, 8>{},  ws + WS_W1, ws + WS_B1);
    layerT(std::integral_constant<int, 16>{}, ws + WS_W2, ws + WS_B2);
    layer3(ws + WS_W3);

    // final: out = relu(A_norm @ hw3 + b3); 8 n-tiles/wave; DIRECT stores
    // from accv (no f32 staging, no further barriers). Per store-instr the
    // wave writes 4 aligned runs of 16 consecutive n (64B f32 / 32B bf16).
    {
        const int rt2 = wave & 3, nt0 = (wave >> 2) * 8;
        short8 aA[2];
#pragma unroll
        for (int h = 0; h < 2; h++)
            aA[h] = *(const short8*)(ws + WS_ADJA + (h * 4 + quad) * 512 + (rt2 * 16 + nl) * 8);
        f32x4 accv[8];
#pragma unroll
        for (int ni = 0; ni < 8; ni++) {
            const int nt = nt0 + ni;
            short8 b0v = *(const short8*)(BUF + (nt * 2 + 0) * 512 + lane * 8);
            short8 b1v = *(const short8*)(BUF + (nt * 2 + 1) * 512 + lane * 8);
            f32x4 a = f32x4{0.f, 0.f, 0.f, 0.f};
            a = __builtin_amdgcn_mfma_f32_16x16x32_bf16(aA[0], b0v, a, 0, 0, 0);
            a = __builtin_amdgcn_mfma_f32_16x16x32_bf16(aA[1], b1v, a, 0, 0, 0);
            accv[ni] = a;
        }
        if (isf32) {
            float* outf = (float*)out + (size_t)bb * 16384;
#pragma unroll
            for (int ni = 0; ni < 8; ni++) {
                const int n = (nt0 + ni) * 16 + nl;
                const float bv = bf2f(ws[WS_B3 + n]);
#pragma unroll
                for (int rr = 0; rr < 4; rr++) {
                    const int m2 = rt2 * 16 + quad * 4 + rr;
                    outf[m2 * 256 + n] = fmaxf(accv[ni][rr] + bv, 0.f);
                }
            }
        } else {
            u16* outu = (u16*)out + (size_t)bb * 16384;
#pragma unroll
            for (int ni = 0; ni < 8; ni++) {
                const int n = (nt0 + ni) * 16 + nl;
                const float bv = bf2f(ws[WS_B3 + n]);
#pragma unroll
                for (int rr = 0; rr < 4; rr++) {
                    const int m2 = rt2 * 16 + quad * 4 + rr;
                    outu[m2 * 256 + n] = f2bf_fast(fmaxf(accv[ni][rr] + bv, 0.f));
                }
            }
        }
    }
}

// ---------------------------------------------------------------------------
extern "C" void kernel_launch(void* const* d_in, const int* in_sizes, int n_in,
                              void* d_out, int out_size, void* d_ws, size_t ws_size,
                              hipStream_t stream) {
    const int* allocs = (const int*)d_in[0];
    const void* qembs = d_in[1];
    const void* dummy = d_in[2];
    const int* eidx   = (const int*)d_in[3];
    const void* ew    = d_in[4];
    const void* W1 = d_in[5];
    const void* b1 = d_in[6];
    const void* W2 = d_in[7];
    const void* b2 = d_in[8];
    const void* W3 = d_in[9];
    const void* b3 = d_in[10];
    u16* ws = (u16*)d_ws;

    prep<<<512, 512, 0, stream>>>(eidx, ew, qembs, dummy, W1, b1, W2, b2, W3, b3, ws);
    fused<<<512, 512, 0, stream>>>(allocs, ws, d_out);
}